// Round 1
// baseline (358.043 us; speedup 1.0000x reference)
//
#include <hip/hip_runtime.h>
#include <hip/hip_bf16.h>
#include <stdint.h>

#define USER_DIM 3706
#define ITEM_DIM 6040
#define LATENT   512
#define BATCH    8192
#define XCOLS    (USER_DIM + ITEM_DIM)   // 9746
#define KPAD_U   3712                     // 116*32
#define KPAD_I   6048                     // 189*32

#define BM 64
#define BN 128
#define BK 32
#define SA_STRIDE 40   // bf16 elems; 80B rows -> conflict-free b128 frag reads
#define SB_STRIDE 40

typedef float f32x4 __attribute__((ext_vector_type(4)));
typedef short bf16x8 __attribute__((ext_vector_type(8)));

static __device__ __forceinline__ unsigned short f2bf(float f) {
    union { float f; unsigned int u; } v; v.f = f;
    unsigned int u = v.u;
    u += 0x7fffu + ((u >> 16) & 1u);   // RNE (inputs are finite)
    return (unsigned short)(u >> 16);
}
static __device__ __forceinline__ float bf2f(unsigned int b) {
    union { unsigned int u; float f; } v; v.u = b << 16; return v.f;
}

// ---- Kernel 1: weight fp32 -> bf16, zero-padded K ----
__global__ void convert_w(const float* __restrict__ W, unsigned short* __restrict__ Wb,
                          int K, int Kpad) {
    int c = blockIdx.x * blockDim.x + threadIdx.x;
    int r = blockIdx.y;
    if (c >= Kpad) return;
    unsigned short o = 0;
    if (c < K) o = f2bf(W[(size_t)r * K + c]);
    Wb[(size_t)r * Kpad + c] = o;
}

// ---- Kernel 2: Emb = relu(X_part @ Wb^T + bias), bf16 out ----
// X: fp32, row stride XCOLS, K valid cols. Wb: [512][Kpad] bf16 zero-padded.
__global__ __launch_bounds__(256, 2) void gemm_relu(
    const float* __restrict__ X, int K, int Kpad,
    const unsigned short* __restrict__ Wb,
    const float* __restrict__ bias,
    unsigned short* __restrict__ Emb)
{
    __shared__ unsigned short sA[BM * SA_STRIDE];
    __shared__ unsigned short sB[BN * SB_STRIDE];

    const int tid  = threadIdx.x;
    const int lane = tid & 63;
    const int wid  = tid >> 6;

    // XCD-chunked swizzle: 512 blocks, 8 XCDs, 64 per XCD; 4 consecutive swz share mb.
    int bid = blockIdx.x;
    int swz = (bid & 7) * (gridDim.x >> 3) + (bid >> 3);
    int mb = swz >> 2;   // 0..127
    int nb = swz & 3;    // 0..3

    // A staging map: thread -> row tid/4 (0..63), colseg (tid%4)*8
    const int ar = tid >> 2;
    const int ac = (tid & 3) * 8;
    const float* xrow = X + (size_t)(mb * BM + ar) * XCOLS + ac;
    // B staging map: thread -> row tid/2 (0..127), colseg (tid%2)*16
    const int br = tid >> 1;
    const int bc = (tid & 1) * 16;
    const unsigned short* wrow = Wb + (size_t)(nb * BN + br) * Kpad + bc;

    unsigned short* sAw = sA + ar * SA_STRIDE + ac;
    unsigned short* sBw = sB + br * SB_STRIDE + bc;

    // fragment read bases: A row = lane%16, k = (lane/16)*8 + j
    const int fr = lane & 15;
    const int fk = (lane >> 4) * 8;
    const unsigned short* sAr = sA + fr * SA_STRIDE + fk;
    const unsigned short* sBr = sB + (wid * 32 + fr) * SB_STRIDE + fk;

    f32x4 acc[4][2];
    #pragma unroll
    for (int i = 0; i < 4; ++i)
        #pragma unroll
        for (int j = 0; j < 2; ++j)
            acc[i][j] = (f32x4)0.0f;

    float a_st[8];
    uint4 b_st0, b_st1;

    auto stage_load = [&](int kt) {
        int kbase = kt * BK;
        if (kbase + BK <= K) {
            float4 v0 = *(const float4*)(xrow + kbase);
            float4 v1 = *(const float4*)(xrow + kbase + 4);
            a_st[0]=v0.x; a_st[1]=v0.y; a_st[2]=v0.z; a_st[3]=v0.w;
            a_st[4]=v1.x; a_st[5]=v1.y; a_st[6]=v1.z; a_st[7]=v1.w;
        } else {
            #pragma unroll
            for (int j = 0; j < 8; ++j) {
                int kg = kbase + ac + j;
                a_st[j] = (kg < K) ? xrow[kbase + j] : 0.0f;
            }
        }
        b_st0 = *(const uint4*)(wrow + kbase);
        b_st1 = *(const uint4*)(wrow + kbase + 8);
    };
    auto stage_write = [&]() {
        uint4 aw;
        aw.x = (unsigned int)f2bf(a_st[0]) | ((unsigned int)f2bf(a_st[1]) << 16);
        aw.y = (unsigned int)f2bf(a_st[2]) | ((unsigned int)f2bf(a_st[3]) << 16);
        aw.z = (unsigned int)f2bf(a_st[4]) | ((unsigned int)f2bf(a_st[5]) << 16);
        aw.w = (unsigned int)f2bf(a_st[6]) | ((unsigned int)f2bf(a_st[7]) << 16);
        *(uint4*)sAw = aw;
        *(uint4*)sBw = b_st0;
        *(uint4*)(sBw + 8) = b_st1;
    };

    const int nt = Kpad / BK;
    stage_load(0);
    stage_write();
    __syncthreads();

    for (int kt = 0; kt < nt; ++kt) {
        bool more = (kt + 1 < nt);
        if (more) stage_load(kt + 1);   // overlap global latency with MFMA

        bf16x8 af[4], bfr[2];
        #pragma unroll
        for (int mi = 0; mi < 4; ++mi)
            af[mi] = *(const bf16x8*)(sAr + mi * 16 * SA_STRIDE);
        #pragma unroll
        for (int ni = 0; ni < 2; ++ni)
            bfr[ni] = *(const bf16x8*)(sBr + ni * 16 * SB_STRIDE);
        #pragma unroll
        for (int mi = 0; mi < 4; ++mi)
            #pragma unroll
            for (int ni = 0; ni < 2; ++ni)
                acc[mi][ni] = __builtin_amdgcn_mfma_f32_16x16x32_bf16(
                    af[mi], bfr[ni], acc[mi][ni], 0, 0, 0);

        __syncthreads();
        if (more) stage_write();
        __syncthreads();
    }

    // epilogue: bias + relu + bf16 store.  D: col = lane&15, row = (lane>>4)*4 + r
    const int c_base = nb * BN + wid * 32;
    const int r_base = mb * BM + (lane >> 4) * 4;
    #pragma unroll
    for (int ni = 0; ni < 2; ++ni) {
        int col = c_base + ni * 16 + fr;
        float bv = bias[col];
        #pragma unroll
        for (int mi = 0; mi < 4; ++mi) {
            f32x4 v = acc[mi][ni];
            #pragma unroll
            for (int r = 0; r < 4; ++r) {
                float val = fmaxf(v[r] + bv, 0.0f);
                int row = r_base + mi * 16 + r;
                Emb[(size_t)row * LATENT + col] = f2bf(val);
            }
        }
    }
}

// ---- Kernel 3: out[b] = sum_d U[b,d]*I[b,d] ----
__global__ void rowdot(const unsigned short* __restrict__ U,
                       const unsigned short* __restrict__ I,
                       float* __restrict__ out) {
    int lane = threadIdx.x & 63;
    int w = threadIdx.x >> 6;
    int row = blockIdx.x * 4 + w;
    const uint4 uv = *(const uint4*)(U + (size_t)row * LATENT + lane * 8);
    const uint4 iv = *(const uint4*)(I + (size_t)row * LATENT + lane * 8);
    const unsigned int* up = (const unsigned int*)&uv;
    const unsigned int* ip = (const unsigned int*)&iv;
    float acc = 0.0f;
    #pragma unroll
    for (int q = 0; q < 4; ++q) {
        acc += bf2f(up[q] & 0xffffu) * bf2f(ip[q] & 0xffffu);
        acc += bf2f(up[q] >> 16)     * bf2f(ip[q] >> 16);
    }
    #pragma unroll
    for (int off = 32; off >= 1; off >>= 1)
        acc += __shfl_xor(acc, off, 64);
    if (lane == 0) out[row] = acc;
}

extern "C" void kernel_launch(void* const* d_in, const int* in_sizes, int n_in,
                              void* d_out, int out_size, void* d_ws, size_t ws_size,
                              hipStream_t stream) {
    const float* x  = (const float*)d_in[0];
    const float* Wu = (const float*)d_in[1];
    const float* bu = (const float*)d_in[2];
    const float* Wi = (const float*)d_in[3];
    const float* bi = (const float*)d_in[4];
    float* out = (float*)d_out;

    unsigned short* WuB  = (unsigned short*)d_ws;                 // 512*3712
    unsigned short* WiB  = WuB + (size_t)LATENT * KPAD_U;         // 512*6048
    unsigned short* Uemb = WiB + (size_t)LATENT * KPAD_I;         // 8192*512
    unsigned short* Iemb = Uemb + (size_t)BATCH * LATENT;         // 8192*512

    convert_w<<<dim3((KPAD_U + 255) / 256, LATENT), 256, 0, stream>>>(Wu, WuB, USER_DIM, KPAD_U);
    convert_w<<<dim3((KPAD_I + 255) / 256, LATENT), 256, 0, stream>>>(Wi, WiB, ITEM_DIM, KPAD_I);

    // user tower: M=8192 (128 mb) x N=512 (4 nb) -> 512 blocks
    gemm_relu<<<512, 256, 0, stream>>>(x, USER_DIM, KPAD_U, WuB, bu, Uemb);
    // item tower
    gemm_relu<<<512, 256, 0, stream>>>(x + USER_DIM, ITEM_DIM, KPAD_I, WiB, bi, Iemb);

    rowdot<<<BATCH / 4, 256, 0, stream>>>(Uemb, Iemb, out);
}